// Round 1
// baseline (416.837 us; speedup 1.0000x reference)
//
#include <hip/hip_runtime.h>

#define N_NODES 50000
#define N_EDGES 640000
// channels: 128 -> 128 -> 128 -> 64, residual 128 -> 64

// ---------------- init / degree / dinv ----------------

__global__ void k_init(int* __restrict__ cnt, int* __restrict__ cursor) {
    int i = blockIdx.x * blockDim.x + threadIdx.x;
    if (i < N_NODES) { cnt[i] = 0; cursor[i] = 0; }
}

__global__ void k_count(const int* __restrict__ ei, int* __restrict__ cnt) {
    int e = blockIdx.x * blockDim.x + threadIdx.x;
    if (e < N_EDGES) atomicAdd(&cnt[ei[N_EDGES + e]], 1);
}

__global__ void k_dinv(const int* __restrict__ cnt, float* __restrict__ dinv) {
    int i = blockIdx.x * blockDim.x + threadIdx.x;
    if (i < N_NODES) dinv[i] = rsqrtf((float)(cnt[i] + 1));  // +1 self-loop, always > 0
}

// ---------------- hierarchical exclusive scan of cnt -> offsets ----------------
// offsets[i] = sum cnt[0..i-1]; offsets[0]=0; offsets[N]=E. 196 blocks x 256.

__global__ void k_scan1(const int* __restrict__ cnt, int* __restrict__ offsets,
                        int* __restrict__ partials) {
    __shared__ int s[256];
    int t = threadIdx.x;
    int i = blockIdx.x * 256 + t;
    int v = (i < N_NODES) ? cnt[i] : 0;
    s[t] = v;
    __syncthreads();
    #pragma unroll
    for (int d = 1; d < 256; d <<= 1) {
        int add = (t >= d) ? s[t - d] : 0;
        __syncthreads();
        s[t] += add;
        __syncthreads();
    }
    if (i < N_NODES) offsets[i + 1] = s[t];   // inclusive within block
    if (t == 255) partials[blockIdx.x] = s[255];
    if (i == 0) offsets[0] = 0;
}

__global__ void k_scan2(int* __restrict__ partials, int nb) {
    __shared__ int s[256];
    int t = threadIdx.x;
    int v = (t < nb) ? partials[t] : 0;
    s[t] = v;
    __syncthreads();
    #pragma unroll
    for (int d = 1; d < 256; d <<= 1) {
        int add = (t >= d) ? s[t - d] : 0;
        __syncthreads();
        s[t] += add;
        __syncthreads();
    }
    if (t < nb) partials[t] = s[t] - v;        // exclusive block bases
}

__global__ void k_scan3(int* __restrict__ offsets, const int* __restrict__ partials) {
    int i = blockIdx.x * 256 + threadIdx.x;
    if (i < N_NODES) offsets[i + 1] += partials[blockIdx.x];
}

// ---------------- CSR fill (keyed by col = destination) ----------------

__global__ void k_fill(const int* __restrict__ ei, const float* __restrict__ dinv,
                       const int* __restrict__ offsets, int* __restrict__ cursor,
                       int* __restrict__ csr_src, float* __restrict__ csr_w) {
    int e = blockIdx.x * blockDim.x + threadIdx.x;
    if (e < N_EDGES) {
        int r = ei[e];
        int c = ei[N_EDGES + e];
        float w = dinv[r] * dinv[c];
        int p = atomicAdd(&cursor[c], 1);
        int idx = offsets[c] + p;
        csr_src[idx] = r;
        csr_w[idx] = w;
    }
}

// ---------------- f32 GEMM: C[N x OUTC] = A[N x 128] @ W[128 x OUTC] (+bias) ----------------
// BM=32 rows/block, W fully staged in LDS, x tile in LDS.
// OUTC=128: 80KB LDS -> 2 blocks/CU. OUTC=64: 48KB -> 3 blocks/CU.

template <int OUTC>
__global__ __launch_bounds__(256, (OUTC == 128 ? 2 : 3))
void k_gemm(const float* __restrict__ A, const float* __restrict__ W,
            const float* __restrict__ bias, float* __restrict__ C) {
    constexpr int CG = OUTC / 4;   // float4 col-groups (32 or 16)
    constexpr int TR = CG / 8;     // rows per thread (4 or 2)
    __shared__ float sW[128 * OUTC];
    __shared__ float sX[32 * 128];

    int t = threadIdx.x;
    int row0 = blockIdx.x * 32;

    // stage W (coalesced float4)
    for (int i = t; i < 128 * OUTC / 4; i += 256)
        ((float4*)sW)[i] = ((const float4*)W)[i];
    // stage x tile: 32 rows x 128 cols = 1024 float4
    for (int i = t; i < 1024; i += 256) {
        int r = i >> 5, c4 = i & 31;
        int gr = row0 + r;
        float4 v = make_float4(0.f, 0.f, 0.f, 0.f);
        if (gr < N_NODES) v = ((const float4*)(A + (size_t)gr * 128))[c4];
        ((float4*)sX)[i] = v;
    }
    __syncthreads();

    int tx = t % CG;       // col group
    int ty = t / CG;       // row group
    float acc[TR][4];
    #pragma unroll
    for (int rr = 0; rr < TR; ++rr) { acc[rr][0]=0.f; acc[rr][1]=0.f; acc[rr][2]=0.f; acc[rr][3]=0.f; }

    #pragma unroll 8
    for (int k = 0; k < 128; ++k) {
        float4 wv = ((const float4*)sW)[k * CG + tx];
        #pragma unroll
        for (int rr = 0; rr < TR; ++rr) {
            float xv = sX[(ty * TR + rr) * 128 + k];
            acc[rr][0] = fmaf(xv, wv.x, acc[rr][0]);
            acc[rr][1] = fmaf(xv, wv.y, acc[rr][1]);
            acc[rr][2] = fmaf(xv, wv.z, acc[rr][2]);
            acc[rr][3] = fmaf(xv, wv.w, acc[rr][3]);
        }
    }

    float4 bv = make_float4(0.f, 0.f, 0.f, 0.f);
    if (bias) bv = ((const float4*)bias)[tx];
    #pragma unroll
    for (int rr = 0; rr < TR; ++rr) {
        int gr = row0 + ty * TR + rr;
        if (gr < N_NODES) {
            float4 o = make_float4(acc[rr][0] + bv.x, acc[rr][1] + bv.y,
                                   acc[rr][2] + bv.z, acc[rr][3] + bv.w);
            ((float4*)(C + (size_t)gr * OUTC))[tx] = o;
        }
    }
}

// ---------------- aggregation: O[v] = sum_{e: col=v} w_e * T[src_e] + dinv[v]^2 * T[v] + bias (+add) ----------------
// one wave per node; CH=128 -> float2/lane, CH=64 -> float/lane. 4-deep load pipeline.

template <int CH, bool RELU, bool HASADD>
__global__ __launch_bounds__(256)
void k_agg(const float* __restrict__ T, const int* __restrict__ offs,
           const int* __restrict__ csr_src, const float* __restrict__ csr_w,
           const float* __restrict__ dinv, const float* __restrict__ bias,
           const float* __restrict__ add, float* __restrict__ O) {
    int lane = threadIdx.x & 63;
    int v = blockIdx.x * 4 + (threadIdx.x >> 6);
    if (v >= N_NODES) return;
    int beg = offs[v], end = offs[v + 1];
    float di = dinv[v];
    float sw = di * di;

    if constexpr (CH == 128) {
        float2 hself = ((const float2*)(T + (size_t)v * 128))[lane];
        float a0 = sw * hself.x, a1 = sw * hself.y;
        int j = beg;
        for (; j + 4 <= end; j += 4) {
            int   s0 = csr_src[j],   s1 = csr_src[j+1], s2 = csr_src[j+2], s3 = csr_src[j+3];
            float w0 = csr_w[j],     w1 = csr_w[j+1],   w2 = csr_w[j+2],   w3 = csr_w[j+3];
            float2 h0 = ((const float2*)(T + (size_t)s0 * 128))[lane];
            float2 h1 = ((const float2*)(T + (size_t)s1 * 128))[lane];
            float2 h2 = ((const float2*)(T + (size_t)s2 * 128))[lane];
            float2 h3 = ((const float2*)(T + (size_t)s3 * 128))[lane];
            a0 = fmaf(w0, h0.x, fmaf(w1, h1.x, fmaf(w2, h2.x, fmaf(w3, h3.x, a0))));
            a1 = fmaf(w0, h0.y, fmaf(w1, h1.y, fmaf(w2, h2.y, fmaf(w3, h3.y, a1))));
        }
        for (; j < end; ++j) {
            int s = csr_src[j]; float w = csr_w[j];
            float2 hh = ((const float2*)(T + (size_t)s * 128))[lane];
            a0 = fmaf(w, hh.x, a0);
            a1 = fmaf(w, hh.y, a1);
        }
        a0 += bias[2 * lane];
        a1 += bias[2 * lane + 1];
        if constexpr (HASADD) {
            a0 += add[(size_t)v * 128 + 2 * lane];
            a1 += add[(size_t)v * 128 + 2 * lane + 1];
        }
        if constexpr (RELU) { a0 = fmaxf(a0, 0.f); a1 = fmaxf(a1, 0.f); }
        ((float2*)(O + (size_t)v * 128))[lane] = make_float2(a0, a1);
    } else {
        // CH == 64
        float a = sw * T[(size_t)v * 64 + lane];
        int j = beg;
        for (; j + 4 <= end; j += 4) {
            int   s0 = csr_src[j],   s1 = csr_src[j+1], s2 = csr_src[j+2], s3 = csr_src[j+3];
            float w0 = csr_w[j],     w1 = csr_w[j+1],   w2 = csr_w[j+2],   w3 = csr_w[j+3];
            float h0 = T[(size_t)s0 * 64 + lane];
            float h1 = T[(size_t)s1 * 64 + lane];
            float h2 = T[(size_t)s2 * 64 + lane];
            float h3 = T[(size_t)s3 * 64 + lane];
            a = fmaf(w0, h0, fmaf(w1, h1, fmaf(w2, h2, fmaf(w3, h3, a))));
        }
        for (; j < end; ++j) {
            int s = csr_src[j]; float w = csr_w[j];
            a = fmaf(w, T[(size_t)s * 64 + lane], a);
        }
        a += bias[lane];
        if constexpr (HASADD) a += add[(size_t)v * 64 + lane];
        if constexpr (RELU) a = fmaxf(a, 0.f);
        O[(size_t)v * 64 + lane] = a;
    }
}

// ---------------- launch ----------------

extern "C" void kernel_launch(void* const* d_in, const int* in_sizes, int n_in,
                              void* d_out, int out_size, void* d_ws, size_t ws_size,
                              hipStream_t stream) {
    const float* x    = (const float*)d_in[0];
    const int*   ei   = (const int*)d_in[1];   // [2, E] flat: row=ei[e], col=ei[E+e]
    const float* W1   = (const float*)d_in[2];
    const float* b1   = (const float*)d_in[3];
    const float* W2   = (const float*)d_in[4];
    const float* b2   = (const float*)d_in[5];
    const float* W3   = (const float*)d_in[6];
    const float* b3   = (const float*)d_in[7];
    const float* Wres = (const float*)d_in[8];
    const float* bres = (const float*)d_in[9];
    float* out = (float*)d_out;

    char* base = (char*)d_ws;
    int*   cnt      = (int*)(base);                        // 200704 B slots
    int*   cursor   = (int*)(base + 200704);
    float* dinv     = (float*)(base + 2 * 200704);
    int*   offsets  = (int*)(base + 3 * 200704);           // N+1 ints
    int*   partials = (int*)(base + 4 * 200704);           // 1024 B
    int*   csr_src  = (int*)(base + 4 * 200704 + 1024);
    float* csr_w    = (float*)(base + 4 * 200704 + 1024 + 2560000);
    float* bufA     = (float*)(base + 4 * 200704 + 1024 + 2 * 2560000);
    float* bufB     = bufA + (size_t)N_NODES * 128;

    const int NB_N = (N_NODES + 255) / 256;   // 196
    const int NB_E = (N_EDGES + 255) / 256;   // 2500
    const int NB_G = (N_NODES + 31) / 32;     // 1563
    const int NB_A = (N_NODES + 3) / 4;       // 12500

    // graph build
    k_init <<<NB_N, 256, 0, stream>>>(cnt, cursor);
    k_count<<<NB_E, 256, 0, stream>>>(ei, cnt);
    k_dinv <<<NB_N, 256, 0, stream>>>(cnt, dinv);
    k_scan1<<<NB_N, 256, 0, stream>>>(cnt, offsets, partials);
    k_scan2<<<1,    256, 0, stream>>>(partials, NB_N);
    k_scan3<<<NB_N, 256, 0, stream>>>(offsets, partials);
    k_fill <<<NB_E, 256, 0, stream>>>(ei, dinv, offsets, cursor, csr_src, csr_w);

    // layer 1: t1 = x@W1 ; h1 = relu(agg(t1)+b1)
    k_gemm<128><<<NB_G, 256, 0, stream>>>(x, W1, nullptr, bufA);
    k_agg<128, true, false><<<NB_A, 256, 0, stream>>>(bufA, offsets, csr_src, csr_w, dinv, b1, nullptr, bufB);
    // layer 2
    k_gemm<128><<<NB_G, 256, 0, stream>>>(bufB, W2, nullptr, bufA);
    k_agg<128, true, false><<<NB_A, 256, 0, stream>>>(bufA, offsets, csr_src, csr_w, dinv, b2, nullptr, bufB);
    // layer 3 (GEMM first -> aggregate only 64 ch) + residual
    k_gemm<64><<<NB_G, 256, 0, stream>>>(bufB, W3, nullptr, bufA);          // t3
    k_gemm<64><<<NB_G, 256, 0, stream>>>(x, Wres, bres, bufB);              // r = x@Wres + bres
    k_agg<64, false, true><<<NB_A, 256, 0, stream>>>(bufA, offsets, csr_src, csr_w, dinv, b3, bufB, out);
}